// Round 1
// baseline (345.767 us; speedup 1.0000x reference)
//
#include <hip/hip_runtime.h>

// ModulatedDeformConv2d forward, fp32, fused sampling + conv.
// Shapes fixed by setup_inputs(): x[8,64,128,128], offset[8,18,128,128],
// mask[8,9,128,128], weight[64,64,3,3], bias[64]; out[8,64,128,128].

constexpr int B    = 8;
constexpr int C    = 64;
constexpr int H    = 128;
constexpr int W    = 128;
constexpr int COUT = 64;
constexpr int K2   = 9;   // 3x3
constexpr int HW   = H * W;

// weight[o][c][k] -> wt[k][c][o]  (o contiguous => s_load_dwordx16 friendly)
__global__ void transpose_w_kernel(const float* __restrict__ w,
                                   float* __restrict__ wt) {
    int idx = blockIdx.x * blockDim.x + threadIdx.x;
    if (idx < COUT * C * K2) {
        int o  = idx / (C * K2);
        int ck = idx % (C * K2);
        int c  = ck / K2;
        int k  = ck % K2;
        wt[(k * C + c) * COUT + o] = w[idx];
    }
}

template <bool TRANSPOSED>
__global__ __launch_bounds__(256) void mdcn_kernel(
    const float* __restrict__ x,
    const float* __restrict__ offset,
    const float* __restrict__ mask,
    const float* __restrict__ wsrc,   // TRANSPOSED ? [k][c][o] : [o][c][k]
    const float* __restrict__ bias,
    float* __restrict__ out) {

    const int p  = blockIdx.x * blockDim.x + threadIdx.x;  // pixel id
    const int wo = p & (W - 1);
    const int ho = (p >> 7) & (H - 1);
    const int b  = p >> 14;

    float acc[COUT];
#pragma unroll
    for (int o = 0; o < COUT; ++o) acc[o] = bias[o];

    const float* xb = x + b * C * HW;

    for (int k = 0; k < K2; ++k) {
        const int ky = k / 3, kx = k % 3;
        // offset layout: [B, 2*K2, H, W]; channel 2k = dx, 2k+1 = dy
        const float dx = offset[((b * 2 * K2 + 2 * k    ) * H + ho) * W + wo];
        const float dy = offset[((b * 2 * K2 + 2 * k + 1) * H + ho) * W + wo];
        const float m  = mask  [((b * K2     + k        ) * H + ho) * W + wo];

        const float py = (float)(ho - 1 + ky) + dy;
        const float px = (float)(wo - 1 + kx) + dx;

        const float y0f = floorf(py), x0f = floorf(px);
        const float wy1 = py - y0f,   wx1 = px - x0f;
        const float wy0 = 1.0f - wy1, wx0 = 1.0f - wx1;
        const int iy0 = (int)y0f, ix0 = (int)x0f;
        const int iy1 = iy0 + 1,  ix1 = ix0 + 1;

        const bool vy0 = (iy0 >= 0) & (iy0 < H);
        const bool vy1 = (iy1 >= 0) & (iy1 < H);
        const bool vx0 = (ix0 >= 0) & (ix0 < W);
        const bool vx1 = (ix1 >= 0) & (ix1 < W);

        // fold mask + per-corner validity into the bilinear weights
        const float w00 = (vy0 & vx0) ? wy0 * wx0 * m : 0.0f;
        const float w01 = (vy0 & vx1) ? wy0 * wx1 * m : 0.0f;
        const float w10 = (vy1 & vx0) ? wy1 * wx0 * m : 0.0f;
        const float w11 = (vy1 & vx1) ? wy1 * wx1 * m : 0.0f;

        const int cy0 = min(max(iy0, 0), H - 1);
        const int cy1 = min(max(iy1, 0), H - 1);
        const int cx0 = min(max(ix0, 0), W - 1);
        const int cx1 = min(max(ix1, 0), W - 1);

        const int o00 = cy0 * W + cx0, o01 = cy0 * W + cx1;
        const int o10 = cy1 * W + cx0, o11 = cy1 * W + cx1;

        for (int c = 0; c < C; ++c) {
            const float* xp = xb + c * HW;
            const float v00 = xp[o00];
            const float v01 = xp[o01];
            const float v10 = xp[o10];
            const float v11 = xp[o11];
            const float val = w00 * v00 + w01 * v01 + w10 * v10 + w11 * v11;

            if (TRANSPOSED) {
                const float* wp = wsrc + (k * C + c) * COUT;  // wave-uniform -> s_load
#pragma unroll
                for (int o = 0; o < COUT; ++o) acc[o] += wp[o] * val;
            } else {
#pragma unroll
                for (int o = 0; o < COUT; ++o)
                    acc[o] += wsrc[(o * C + c) * K2 + k] * val;
            }
        }
    }

    float* op = out + (b * COUT) * HW + ho * W + wo;
#pragma unroll
    for (int o = 0; o < COUT; ++o) op[o * HW] = acc[o];
}

extern "C" void kernel_launch(void* const* d_in, const int* in_sizes, int n_in,
                              void* d_out, int out_size, void* d_ws, size_t ws_size,
                              hipStream_t stream) {
    const float* x      = (const float*)d_in[0];
    const float* offset = (const float*)d_in[1];
    const float* mask   = (const float*)d_in[2];
    const float* weight = (const float*)d_in[3];
    const float* bias   = (const float*)d_in[4];
    float* out          = (float*)d_out;

    const int n_pix   = B * H * W;            // 131072
    const int n_block = n_pix / 256;          // 512

    const size_t wt_bytes = (size_t)COUT * C * K2 * sizeof(float);  // 147456
    if (ws_size >= wt_bytes) {
        float* wt = (float*)d_ws;
        transpose_w_kernel<<<(COUT * C * K2 + 255) / 256, 256, 0, stream>>>(weight, wt);
        mdcn_kernel<true><<<n_block, 256, 0, stream>>>(x, offset, mask, wt, bias, out);
    } else {
        mdcn_kernel<false><<<n_block, 256, 0, stream>>>(x, offset, mask, weight, bias, out);
    }
}

// Round 2
// 305.870 us; speedup vs baseline: 1.1304x; 1.1304x over previous
//
#include <hip/hip_runtime.h>
#include <hip/hip_bf16.h>

// ModulatedDeformConv2d forward, fused sampling + bf16-MFMA conv.
// x[8,64,128,128] f32, offset[8,18,128,128], mask[8,9,128,128],
// weight[64,64,3,3], bias[64]; out[8,64,128,128] f32.

constexpr int B    = 8;
constexpr int C    = 64;
constexpr int H    = 128;
constexpr int W    = 128;
constexpr int COUT = 64;
constexpr int K2   = 9;
constexpr int HW   = H * W;

typedef __attribute__((ext_vector_type(8))) short bf16x8;
typedef __attribute__((ext_vector_type(4))) short s16x4;
typedef __attribute__((ext_vector_type(4))) float f32x4;

// LDS B-tile: s[128 px][64 c] bf16, padded to 72 shorts (144 B) per row so
// 16-px-apart B-frag ds_read_b128 is only 2-way bank aliased (free on CDNA4).
constexpr int LDSS = 72;

// ---------- x: NCHW -> NHWC ----------
__global__ __launch_bounds__(256) void transpose_x_kernel(
    const float* __restrict__ x, float* __restrict__ xt) {
    __shared__ float t[64][65];
    const int blk  = blockIdx.x;          // B * (HW/64) = 2048
    const int b    = blk >> 8;
    const int hwb  = (blk & 255) * 64;
    const int lane = threadIdx.x & 63;
    const int grp  = threadIdx.x >> 6;    // 0..3
    const float* xb = x + (size_t)b * C * HW;
#pragma unroll
    for (int r = 0; r < 16; ++r) {
        const int c = grp * 16 + r;
        t[c][lane] = xb[c * HW + hwb + lane];   // coalesced along hw
    }
    __syncthreads();
    float* xo = xt + (size_t)b * HW * C;
#pragma unroll
    for (int r = 0; r < 16; ++r) {
        const int hw_l = grp * 16 + r;
        xo[(size_t)(hwb + hw_l) * C + lane] = t[lane][hw_l];  // coalesced along c
    }
}

// ---------- weight[o][c][3][3] f32 -> A-fragment-ordered bf16 ----------
// wfrag[((k*2+kk)*4+mt)*64 + lane][j] = bf16( w[m][c][k] )
//   m = mt*16 + (lane&15), q = lane>>4, c = kk*32 + q*8 + j
__global__ __launch_bounds__(256) void pack_w_kernel(
    const float* __restrict__ w, short* __restrict__ wfrag) {
    int id = blockIdx.x * blockDim.x + threadIdx.x;   // 36864 total
    if (id >= COUT * C * K2) return;
    const int j    = id & 7;
    const int lane = (id >> 3) & 63;
    const int mt   = (id >> 9) & 3;
    const int kk   = (id >> 11) & 1;
    const int k    = id >> 12;                        // 0..8
    const int m    = mt * 16 + (lane & 15);
    const int q    = lane >> 4;
    const int c    = kk * 32 + q * 8 + j;
    const float v  = w[(m * C + c) * K2 + k];
    union { __hip_bfloat16 h; short s; } u;
    u.h = __float2bfloat16(v);
    wfrag[id] = u.s;
}

// ---------- fused sample + MFMA GEMM ----------
__global__ __launch_bounds__(256, 4) void mdcn_mfma_kernel(
    const float* __restrict__ xt,      // [B][H][W][C]
    const float* __restrict__ offset,
    const float* __restrict__ mask,
    const short* __restrict__ wfrag,
    const float* __restrict__ bias,
    float* __restrict__ out) {

    __shared__ short smem[128 * LDSS];   // 18 KB

    const int tid  = threadIdx.x;
    const int wg   = blockIdx.x;         // 0..1023
    const int ho   = wg & (H - 1);
    const int b    = wg >> 7;
    const int wave = tid >> 6;
    const int lane = tid & 63;
    const int col  = lane & 15;
    const int q    = lane >> 4;

    // sampling mapping: 2 threads per pixel (c-halves)
    const int spx = tid >> 1;            // 0..127 == wo
    const int c0  = (tid & 1) * 32;

    const float* xb = xt + (size_t)b * HW * C;

    f32x4 acc[4][2];
#pragma unroll
    for (int mt = 0; mt < 4; ++mt)
#pragma unroll
        for (int n = 0; n < 2; ++n) acc[mt][n] = (f32x4)0.0f;

    for (int k = 0; k < K2; ++k) {
        // ---- sample 128 px x 64 c into LDS as bf16 ----
        const int ky = k / 3, kx = k % 3;
        const float dx = offset[((b * 2 * K2 + 2 * k    ) * H + ho) * W + spx];
        const float dy = offset[((b * 2 * K2 + 2 * k + 1) * H + ho) * W + spx];
        const float mm = mask  [((b * K2     + k        ) * H + ho) * W + spx];

        const float py = (float)(ho - 1 + ky) + dy;
        const float px = (float)(spx - 1 + kx) + dx;
        const float y0f = floorf(py), x0f = floorf(px);
        const float wy1 = py - y0f,   wx1 = px - x0f;
        const float wy0 = 1.0f - wy1, wx0 = 1.0f - wx1;
        const int iy0 = (int)y0f, ix0 = (int)x0f;
        const int iy1 = iy0 + 1,  ix1 = ix0 + 1;
        const bool vy0 = (iy0 >= 0) & (iy0 < H);
        const bool vy1 = (iy1 >= 0) & (iy1 < H);
        const bool vx0 = (ix0 >= 0) & (ix0 < W);
        const bool vx1 = (ix1 >= 0) & (ix1 < W);
        const float w00 = (vy0 & vx0) ? wy0 * wx0 * mm : 0.0f;
        const float w01 = (vy0 & vx1) ? wy0 * wx1 * mm : 0.0f;
        const float w10 = (vy1 & vx0) ? wy1 * wx0 * mm : 0.0f;
        const float w11 = (vy1 & vx1) ? wy1 * wx1 * mm : 0.0f;
        const int cy0 = min(max(iy0, 0), H - 1);
        const int cy1 = min(max(iy1, 0), H - 1);
        const int cx0 = min(max(ix0, 0), W - 1);
        const int cx1 = min(max(ix1, 0), W - 1);

        const f32x4* p00 = (const f32x4*)(xb + (size_t)(cy0 * W + cx0) * C + c0);
        const f32x4* p01 = (const f32x4*)(xb + (size_t)(cy0 * W + cx1) * C + c0);
        const f32x4* p10 = (const f32x4*)(xb + (size_t)(cy1 * W + cx0) * C + c0);
        const f32x4* p11 = (const f32x4*)(xb + (size_t)(cy1 * W + cx1) * C + c0);

        short* sdst = smem + spx * LDSS + c0;
#pragma unroll
        for (int j = 0; j < 8; ++j) {
            const f32x4 v = p00[j] * w00 + p01[j] * w01 + p10[j] * w10 + p11[j] * w11;
            union { __hip_bfloat162 h2[2]; s16x4 s; } cvt;
            cvt.h2[0] = __float22bfloat162_rn(float2{v.x, v.y});
            cvt.h2[1] = __float22bfloat162_rn(float2{v.z, v.w});
            *(s16x4*)(sdst + j * 4) = cvt.s;
        }
        __syncthreads();

        // ---- MFMA: out[64 o][128 px] += W[64 o][64 c] * S[64 c][128 px] ----
        const bf16x8* wf = (const bf16x8*)wfrag;
#pragma unroll
        for (int kk = 0; kk < 2; ++kk) {
            bf16x8 bfrag[2];
#pragma unroll
            for (int n = 0; n < 2; ++n) {
                const int pxn = (wave * 2 + n) * 16 + col;
                bfrag[n] = *(const bf16x8*)(smem + pxn * LDSS + kk * 32 + q * 8);
            }
#pragma unroll
            for (int mt = 0; mt < 4; ++mt) {
                const bf16x8 afrag = wf[((k * 2 + kk) * 4 + mt) * 64 + lane];
#pragma unroll
                for (int n = 0; n < 2; ++n)
                    acc[mt][n] = __builtin_amdgcn_mfma_f32_16x16x32_bf16(
                        afrag, bfrag[n], acc[mt][n], 0, 0, 0);
            }
        }
        __syncthreads();
    }

    // ---- epilogue: D row=(q*4+reg) -> o, col -> wo ----
#pragma unroll
    for (int mt = 0; mt < 4; ++mt) {
#pragma unroll
        for (int n = 0; n < 2; ++n) {
            const int wo = (wave * 2 + n) * 16 + col;
#pragma unroll
            for (int r = 0; r < 4; ++r) {
                const int o = mt * 16 + q * 4 + r;
                out[(((size_t)b * COUT + o) * H + ho) * W + wo] = acc[mt][n][r] + bias[o];
            }
        }
    }
}

// ---------- fallback (round-1 direct kernel, no workspace needed) ----------
__global__ __launch_bounds__(256) void mdcn_direct_kernel(
    const float* __restrict__ x, const float* __restrict__ offset,
    const float* __restrict__ mask, const float* __restrict__ wsrc,
    const float* __restrict__ bias, float* __restrict__ out) {
    const int p  = blockIdx.x * blockDim.x + threadIdx.x;
    const int wo = p & (W - 1);
    const int ho = (p >> 7) & (H - 1);
    const int b  = p >> 14;
    float acc[COUT];
#pragma unroll
    for (int o = 0; o < COUT; ++o) acc[o] = bias[o];
    const float* xb = x + b * C * HW;
    for (int k = 0; k < K2; ++k) {
        const int ky = k / 3, kx = k % 3;
        const float dx = offset[((b * 2 * K2 + 2 * k    ) * H + ho) * W + wo];
        const float dy = offset[((b * 2 * K2 + 2 * k + 1) * H + ho) * W + wo];
        const float m  = mask  [((b * K2     + k        ) * H + ho) * W + wo];
        const float py = (float)(ho - 1 + ky) + dy;
        const float px = (float)(wo - 1 + kx) + dx;
        const float y0f = floorf(py), x0f = floorf(px);
        const float wy1 = py - y0f, wx1 = px - x0f;
        const float wy0 = 1.0f - wy1, wx0 = 1.0f - wx1;
        const int iy0 = (int)y0f, ix0 = (int)x0f;
        const int iy1 = iy0 + 1, ix1 = ix0 + 1;
        const bool vy0 = (iy0 >= 0) & (iy0 < H);
        const bool vy1 = (iy1 >= 0) & (iy1 < H);
        const bool vx0 = (ix0 >= 0) & (ix0 < W);
        const bool vx1 = (ix1 >= 0) & (ix1 < W);
        const float w00 = (vy0 & vx0) ? wy0 * wx0 * m : 0.0f;
        const float w01 = (vy0 & vx1) ? wy0 * wx1 * m : 0.0f;
        const float w10 = (vy1 & vx0) ? wy1 * wx0 * m : 0.0f;
        const float w11 = (vy1 & vx1) ? wy1 * wx1 * m : 0.0f;
        const int cy0 = min(max(iy0, 0), H - 1);
        const int cy1 = min(max(iy1, 0), H - 1);
        const int cx0 = min(max(ix0, 0), W - 1);
        const int cx1 = min(max(ix1, 0), W - 1);
        const int o00 = cy0 * W + cx0, o01 = cy0 * W + cx1;
        const int o10 = cy1 * W + cx0, o11 = cy1 * W + cx1;
        for (int c = 0; c < C; ++c) {
            const float* xp = xb + c * HW;
            const float val = w00 * xp[o00] + w01 * xp[o01] +
                              w10 * xp[o10] + w11 * xp[o11];
#pragma unroll
            for (int o = 0; o < COUT; ++o)
                acc[o] += wsrc[(o * C + c) * K2 + k] * val;
        }
    }
    float* op = out + ((size_t)b * COUT) * HW + ho * W + wo;
#pragma unroll
    for (int o = 0; o < COUT; ++o) op[o * HW] = acc[o];
}

extern "C" void kernel_launch(void* const* d_in, const int* in_sizes, int n_in,
                              void* d_out, int out_size, void* d_ws, size_t ws_size,
                              hipStream_t stream) {
    const float* x      = (const float*)d_in[0];
    const float* offset = (const float*)d_in[1];
    const float* mask   = (const float*)d_in[2];
    const float* weight = (const float*)d_in[3];
    const float* bias   = (const float*)d_in[4];
    float* out          = (float*)d_out;

    const size_t xt_bytes = (size_t)B * HW * C * sizeof(float);   // 33.55 MB
    const size_t wf_bytes = (size_t)COUT * C * K2 * sizeof(short);
    if (ws_size >= xt_bytes + wf_bytes) {
        float* xt    = (float*)d_ws;
        short* wfrag = (short*)((char*)d_ws + xt_bytes);
        transpose_x_kernel<<<B * (HW / 64), 256, 0, stream>>>(x, xt);
        pack_w_kernel<<<(COUT * C * K2 + 255) / 256, 256, 0, stream>>>(weight, wfrag);
        mdcn_mfma_kernel<<<B * H, 256, 0, stream>>>(xt, offset, mask, wfrag, bias, out);
    } else {
        mdcn_direct_kernel<<<(B * HW) / 256, 256, 0, stream>>>(
            x, offset, mask, weight, bias, out);
    }
}

// Round 3
// 152.662 us; speedup vs baseline: 2.2649x; 2.0036x over previous
//
#include <hip/hip_runtime.h>
#include <hip/hip_bf16.h>

// ModulatedDeformConv2d forward: bf16 NHWC x + XCD-swizzled fused sample+MFMA.
// x[8,64,128,128] f32, offset[8,18,128,128], mask[8,9,128,128],
// weight[64,64,3,3], bias[64]; out[8,64,128,128] f32.

constexpr int B    = 8;
constexpr int C    = 64;
constexpr int H    = 128;
constexpr int W    = 128;
constexpr int COUT = 64;
constexpr int K2   = 9;
constexpr int HW   = H * W;

typedef __attribute__((ext_vector_type(8))) short bf16x8;
typedef __attribute__((ext_vector_type(4))) float f32x4;

// LDS sample tile: s[64 px][64 c] bf16, row padded 64->72 shorts (144 B) so
// both the 32B staging writes and 16-px-strided B-frag ds_read_b128 hit the
// minimum bank aliasing.
constexpr int LDSS = 72;

// ---------- x: NCHW f32 -> NHWC bf16 ----------
__global__ __launch_bounds__(256) void transpose_x_kernel(
    const float* __restrict__ x, short* __restrict__ xt) {
    __shared__ float tbuf[64][65];
    const int blk  = blockIdx.x;          // B * (HW/64) = 2048
    const int b    = blk >> 8;
    const int hwb  = (blk & 255) * 64;
    const int lane = threadIdx.x & 63;
    const int grp  = threadIdx.x >> 6;    // 0..3
    const float* xb = x + (size_t)b * C * HW;
#pragma unroll
    for (int r = 0; r < 16; ++r) {
        const int c = grp * 16 + r;
        tbuf[c][lane] = xb[c * HW + hwb + lane];   // coalesced along hw
    }
    __syncthreads();
    short* xo = xt + (size_t)b * HW * C;
#pragma unroll
    for (int r = 0; r < 16; ++r) {
        const int hw_l = grp * 16 + r;
        union { __hip_bfloat16 h; short s; } u;
        u.h = __float2bfloat16(tbuf[lane][hw_l]);
        xo[(size_t)(hwb + hw_l) * C + lane] = u.s;  // coalesced along c
    }
}

// ---------- weight[o][c][3][3] f32 -> A-fragment-ordered bf16 ----------
// wfrag[((k*2+kk)*4+mt)*64 + lane][j] = bf16( w[m][c][k] )
//   m = mt*16 + (lane&15), q = lane>>4, c = kk*32 + q*8 + j
__global__ __launch_bounds__(256) void pack_w_kernel(
    const float* __restrict__ w, short* __restrict__ wfrag) {
    int id = blockIdx.x * blockDim.x + threadIdx.x;
    if (id >= COUT * C * K2) return;
    const int j    = id & 7;
    const int lane = (id >> 3) & 63;
    const int mt   = (id >> 9) & 3;
    const int kk   = (id >> 11) & 1;
    const int k    = id >> 12;
    const int m    = mt * 16 + (lane & 15);
    const int q    = lane >> 4;
    const int c    = kk * 32 + q * 8 + j;
    union { __hip_bfloat16 h; short s; } u;
    u.h = __float2bfloat16(w[(m * C + c) * K2 + k]);
    wfrag[id] = u.s;
}

// ---------- fused sample + MFMA GEMM ----------
// grid 2048: wg -> b = wg&7 (XCD-aware: round-robin puts batch b on XCD b,
// whose bf16 x (2.1 MB) fits the 4 MB per-XCD L2), t = wg>>3 -> (ho, 64px half).
__global__ __launch_bounds__(256, 6) void mdcn_mfma_kernel(
    const short* __restrict__ xt,      // [B][H][W][C] bf16
    const float* __restrict__ offset,
    const float* __restrict__ mask,
    const short* __restrict__ wfrag,
    const float* __restrict__ bias,
    float* __restrict__ out) {

    __shared__ short smem[64 * LDSS];        // 9216 B
    __shared__ float offs[2 * K2 * 64];      // 4608 B
    __shared__ float msks[K2 * 64];          // 2304 B

    const int wg   = blockIdx.x;
    const int b    = wg & 7;
    const int t    = wg >> 3;                // 0..255
    const int ho   = t >> 1;
    const int px0  = (t & 1) * 64;

    const int tid  = threadIdx.x;
    const int wave = tid >> 6;
    const int lane = tid & 63;
    const int col  = lane & 15;
    const int q    = lane >> 4;
    const int spx  = tid >> 2;               // 0..63 pixel within tile
    const int cq   = (tid & 3) * 16;         // channel quarter

    // ---- stage all offsets/masks for this (b, ho, px0) tile ----
    for (int f = tid; f < 2 * K2 * 64; f += 256) {
        const int ch = f >> 6, i = f & 63;
        offs[f] = offset[(((size_t)b * 2 * K2 + ch) * H + ho) * W + px0 + i];
    }
    for (int f = tid; f < K2 * 64; f += 256) {
        const int ch = f >> 6, i = f & 63;
        msks[f] = mask[(((size_t)b * K2 + ch) * H + ho) * W + px0 + i];
    }

    const short* xb = xt + (size_t)b * HW * C;
    f32x4 acc[4];
#pragma unroll
    for (int mt = 0; mt < 4; ++mt) acc[mt] = (f32x4)0.0f;

    __syncthreads();

    for (int k = 0; k < K2; ++k) {
        const int ky = k / 3, kx = k % 3;
        const float dx = offs[(2 * k    ) * 64 + spx];
        const float dy = offs[(2 * k + 1) * 64 + spx];
        const float mm = msks[k * 64 + spx];
        const int wo = px0 + spx;

        const float py = (float)(ho - 1 + ky) + dy;
        const float px = (float)(wo - 1 + kx) + dx;
        const float y0f = floorf(py), x0f = floorf(px);
        const float wy1 = py - y0f,   wx1 = px - x0f;
        const float wy0 = 1.0f - wy1, wx0 = 1.0f - wx1;
        const int iy0 = (int)y0f, ix0 = (int)x0f;
        const int iy1 = iy0 + 1,  ix1 = ix0 + 1;
        const bool vy0 = (iy0 >= 0) & (iy0 < H);
        const bool vy1 = (iy1 >= 0) & (iy1 < H);
        const bool vx0 = (ix0 >= 0) & (ix0 < W);
        const bool vx1 = (ix1 >= 0) & (ix1 < W);
        const float w00 = (vy0 & vx0) ? wy0 * wx0 * mm : 0.0f;
        const float w01 = (vy0 & vx1) ? wy0 * wx1 * mm : 0.0f;
        const float w10 = (vy1 & vx0) ? wy1 * wx0 * mm : 0.0f;
        const float w11 = (vy1 & vx1) ? wy1 * wx1 * mm : 0.0f;
        const int cy0 = min(max(iy0, 0), H - 1);
        const int cy1 = min(max(iy1, 0), H - 1);
        const int cx0 = min(max(ix0, 0), W - 1);
        const int cx1 = min(max(ix1, 0), W - 1);

        const short* s00 = xb + (cy0 * W + cx0) * C + cq;
        const short* s01 = xb + (cy0 * W + cx1) * C + cq;
        const short* s10 = xb + (cy1 * W + cx0) * C + cq;
        const short* s11 = xb + (cy1 * W + cx1) * C + cq;

        bf16x8 g00[2], g01[2], g10[2], g11[2];
#pragma unroll
        for (int j = 0; j < 2; ++j) {
            g00[j] = *(const bf16x8*)(s00 + j * 8);
            g01[j] = *(const bf16x8*)(s01 + j * 8);
            g10[j] = *(const bf16x8*)(s10 + j * 8);
            g11[j] = *(const bf16x8*)(s11 + j * 8);
        }

        short* sdst = smem + spx * LDSS + cq;
#pragma unroll
        for (int j = 0; j < 2; ++j) {
            union U8 { bf16x8 s; __hip_bfloat162 h2[4]; };
            U8 u00{g00[j]}, u01{g01[j]}, u10{g10[j]}, u11{g11[j]}, r;
#pragma unroll
            for (int p = 0; p < 4; ++p) {
                const float2 f00 = __bfloat1622float2(u00.h2[p]);
                const float2 f01 = __bfloat1622float2(u01.h2[p]);
                const float2 f10 = __bfloat1622float2(u10.h2[p]);
                const float2 f11 = __bfloat1622float2(u11.h2[p]);
                float2 v;
                v.x = w00 * f00.x + w01 * f01.x + w10 * f10.x + w11 * f11.x;
                v.y = w00 * f00.y + w01 * f01.y + w10 * f10.y + w11 * f11.y;
                r.h2[p] = __float22bfloat162_rn(v);
            }
            *(bf16x8*)(sdst + j * 8) = r.s;
        }
        __syncthreads();

        // ---- MFMA: out[64 o][64 px] += W[64 o][64 c] * S[64 c][64 px] ----
        const bf16x8* wf = (const bf16x8*)wfrag;
#pragma unroll
        for (int kk = 0; kk < 2; ++kk) {
            const bf16x8 bfrag =
                *(const bf16x8*)(smem + (wave * 16 + col) * LDSS + kk * 32 + q * 8);
#pragma unroll
            for (int mt = 0; mt < 4; ++mt) {
                const bf16x8 afrag = wf[((k * 2 + kk) * 4 + mt) * 64 + lane];
                acc[mt] = __builtin_amdgcn_mfma_f32_16x16x32_bf16(
                    afrag, bfrag, acc[mt], 0, 0, 0);
            }
        }
        __syncthreads();
    }

    // ---- epilogue: D row=(q*4+reg) -> o, col -> px ----
    const int wo = px0 + wave * 16 + col;
#pragma unroll
    for (int mt = 0; mt < 4; ++mt) {
#pragma unroll
        for (int r = 0; r < 4; ++r) {
            const int o = mt * 16 + q * 4 + r;
            out[(((size_t)b * COUT + o) * H + ho) * W + wo] = acc[mt][r] + bias[o];
        }
    }
}

// ---------- fallback (direct, no workspace) ----------
__global__ __launch_bounds__(256) void mdcn_direct_kernel(
    const float* __restrict__ x, const float* __restrict__ offset,
    const float* __restrict__ mask, const float* __restrict__ wsrc,
    const float* __restrict__ bias, float* __restrict__ out) {
    const int p  = blockIdx.x * blockDim.x + threadIdx.x;
    const int wo = p & (W - 1);
    const int ho = (p >> 7) & (H - 1);
    const int b  = p >> 14;
    float acc[COUT];
#pragma unroll
    for (int o = 0; o < COUT; ++o) acc[o] = bias[o];
    const float* xb = x + b * C * HW;
    for (int k = 0; k < K2; ++k) {
        const int ky = k / 3, kx = k % 3;
        const float dx = offset[((b * 2 * K2 + 2 * k    ) * H + ho) * W + wo];
        const float dy = offset[((b * 2 * K2 + 2 * k + 1) * H + ho) * W + wo];
        const float m  = mask  [((b * K2     + k        ) * H + ho) * W + wo];
        const float py = (float)(ho - 1 + ky) + dy;
        const float px = (float)(wo - 1 + kx) + dx;
        const float y0f = floorf(py), x0f = floorf(px);
        const float wy1 = py - y0f, wx1 = px - x0f;
        const float wy0 = 1.0f - wy1, wx0 = 1.0f - wx1;
        const int iy0 = (int)y0f, ix0 = (int)x0f;
        const int iy1 = iy0 + 1, ix1 = ix0 + 1;
        const bool vy0 = (iy0 >= 0) & (iy0 < H);
        const bool vy1 = (iy1 >= 0) & (iy1 < H);
        const bool vx0 = (ix0 >= 0) & (ix0 < W);
        const bool vx1 = (ix1 >= 0) & (ix1 < W);
        const float w00 = (vy0 & vx0) ? wy0 * wx0 * m : 0.0f;
        const float w01 = (vy0 & vx1) ? wy0 * wx1 * m : 0.0f;
        const float w10 = (vy1 & vx0) ? wy1 * wx0 * m : 0.0f;
        const float w11 = (vy1 & vx1) ? wy1 * wx1 * m : 0.0f;
        const int cy0 = min(max(iy0, 0), H - 1);
        const int cy1 = min(max(iy1, 0), H - 1);
        const int cx0 = min(max(ix0, 0), W - 1);
        const int cx1 = min(max(ix1, 0), W - 1);
        const int o00 = cy0 * W + cx0, o01 = cy0 * W + cx1;
        const int o10 = cy1 * W + cx0, o11 = cy1 * W + cx1;
        for (int c = 0; c < C; ++c) {
            const float* xp = xb + c * HW;
            const float val = w00 * xp[o00] + w01 * xp[o01] +
                              w10 * xp[o10] + w11 * xp[o11];
#pragma unroll
            for (int o = 0; o < COUT; ++o)
                acc[o] += wsrc[(o * C + c) * K2 + k] * val;
        }
    }
    float* op = out + ((size_t)b * COUT) * HW + ho * W + wo;
#pragma unroll
    for (int o = 0; o < COUT; ++o) op[o * HW] = acc[o];
}

extern "C" void kernel_launch(void* const* d_in, const int* in_sizes, int n_in,
                              void* d_out, int out_size, void* d_ws, size_t ws_size,
                              hipStream_t stream) {
    const float* x      = (const float*)d_in[0];
    const float* offset = (const float*)d_in[1];
    const float* mask   = (const float*)d_in[2];
    const float* weight = (const float*)d_in[3];
    const float* bias   = (const float*)d_in[4];
    float* out          = (float*)d_out;

    const size_t xt_bytes = (size_t)B * HW * C * sizeof(short);   // 16.78 MB
    const size_t wf_bytes = (size_t)COUT * C * K2 * sizeof(short);
    if (ws_size >= xt_bytes + wf_bytes) {
        short* xt    = (short*)d_ws;
        short* wfrag = (short*)((char*)d_ws + xt_bytes);
        transpose_x_kernel<<<B * (HW / 64), 256, 0, stream>>>(x, xt);
        pack_w_kernel<<<(COUT * C * K2 + 255) / 256, 256, 0, stream>>>(weight, wfrag);
        mdcn_mfma_kernel<<<2 * B * H, 256, 0, stream>>>(xt, offset, mask, wfrag, bias, out);
    } else {
        mdcn_direct_kernel<<<(B * HW) / 256, 256, 0, stream>>>(
            x, offset, mask, weight, bias, out);
    }
}